// Round 11
// baseline (505.615 us; speedup 1.0000x reference)
//
#include <hip/hip_runtime.h>

// ---------------------------------------------------------------------------
// SimpleEquivariantNetwork: 3-layer equivariant message passing.
//   Bilinearity: aggregate raw h first, contract with W_tp after:
//     h_new[d,k] = sum_i sum_a W[i,a,k] * Agg[d,a,i],
//     Agg[d,a,i] = sum_{e->d} c_e * attr[e,a] * h[src_e, i]
//   Setup: radial_tab, counting-sort by dst (hist/scan/place), fill (cattr4),
//          embed (h fp32 + bf16-packed hb0).
//   Per layer: agg_tp_k, chunk-8 edge loop:
//     phase1: one coalesced index load (8 idx) + static shfl extract
//     phase2: 8 independent hb gathers + 8 cattr4 broadcasts, all in flight
//     phase3: predicated FMA block; then shfl-contract with W_tp; repack hb.
//   pool_k / final_k as before.
// ---------------------------------------------------------------------------

constexpr int Dk  = 32;   // feature dim D
constexpr int Hk  = 64;   // radial hidden
constexpr int NBk = 10;   // radial basis
constexpr int Lk  = 3;    // layers
constexpr int FinK = 16;  // input features
constexpr int TAB = 8192; // radial table intervals over [0,5]
constexpr int SCB = 256;  // scan block size

__device__ __forceinline__ float sus(float x) {
    return x > 0.f ? __expf(-1.f / x) : 0.f;
}

__device__ __forceinline__ unsigned pack_bf16_rne(float a, float b) {
    unsigned ua = __float_as_uint(a), ub = __float_as_uint(b);
    ua += 0x7FFFu + ((ua >> 16) & 1u);
    ub += 0x7FFFu + ((ub >> 16) & 1u);
    return (ua >> 16) | (ub & 0xFFFF0000u);
}

// ---- radial table ----------------------------------------------------------
__global__ __launch_bounds__(256) void radial_tab_k(
    const float* __restrict__ Wfc1, const float* __restrict__ Wfc2,
    float* __restrict__ rtab)
{
    int l = blockIdx.y;
    __shared__ float sW1[NBk * Hk];
    __shared__ float sW2[Hk];
    for (int j = threadIdx.x; j < NBk * Hk; j += blockDim.x) sW1[j] = Wfc1[l * NBk * Hk + j];
    for (int j = threadIdx.x; j < Hk; j += blockDim.x) sW2[j] = Wfc2[l * Hk + j];
    __syncthreads();

    int i = blockIdx.x * blockDim.x + threadIdx.x;
    if (i > TAB) return;
    float len = 5.f * (float)i / (float)TAB;
    const float C_EMB = (float)(1.14136 * 7.3890560989306495);
    float t = len * 2.2f;
    float emb[NBk];
#pragma unroll
    for (int j = 0; j < NBk; j++) {
        float d1 = t - (float)j;
        float d2 = (float)(j + 2) - t;
        emb[j] = C_EMB * sus(d1) * sus(d2);
    }
    const float C_OUT = (float)(0.125 * 0.08838834764831845 * 0.2581988897471611);
    float r = 0.f;
    for (int j = 0; j < Hk; j++) {
        float a = 0.f;
#pragma unroll
        for (int b = 0; b < NBk; b++) a += emb[b] * sW1[b * Hk + j];
        float sg = 1.f / (1.f + __expf(-a));
        r += a * sg * sW2[j];
    }
    rtab[l * (TAB + 1) + i] = r * C_OUT;
}

// ---- counting sort by dst --------------------------------------------------
__global__ __launch_bounds__(256) void hist_k(
    const int* __restrict__ edst, int* __restrict__ deg, int E)
{
    int e = blockIdx.x * blockDim.x + threadIdx.x;
    if (e < E) atomicAdd(&deg[edst[e]], 1);
}

__global__ __launch_bounds__(SCB) void scan1_k(
    const int* __restrict__ deg, int* __restrict__ incl,
    int* __restrict__ bsum, int N)
{
    __shared__ int s[SCB];
    int g = blockIdx.x * SCB + threadIdx.x;
    s[threadIdx.x] = (g < N) ? deg[g] : 0;
    __syncthreads();
    for (int off = 1; off < SCB; off <<= 1) {
        int t = (threadIdx.x >= off) ? s[threadIdx.x - off] : 0;
        __syncthreads();
        s[threadIdx.x] += t;
        __syncthreads();
    }
    if (g < N) incl[g] = s[threadIdx.x];
    if (threadIdx.x == SCB - 1) bsum[blockIdx.x] = s[threadIdx.x];
}

__global__ __launch_bounds__(512) void scan2_k(int* __restrict__ bsum, int nb)
{
    __shared__ int s[512];
    s[threadIdx.x] = (threadIdx.x < nb) ? bsum[threadIdx.x] : 0;
    __syncthreads();
    for (int off = 1; off < 512; off <<= 1) {
        int t = (threadIdx.x >= off) ? s[threadIdx.x - off] : 0;
        __syncthreads();
        s[threadIdx.x] += t;
        __syncthreads();
    }
    if (threadIdx.x < nb) bsum[threadIdx.x] = s[threadIdx.x];
}

__global__ __launch_bounds__(SCB) void scan3_k(
    const int* __restrict__ deg, const int* __restrict__ incl,
    const int* __restrict__ bsum, int* __restrict__ row_ptr,
    int* __restrict__ cur, int N, int E)
{
    int g = blockIdx.x * SCB + threadIdx.x;
    if (g < N) {
        int off = (blockIdx.x > 0) ? bsum[blockIdx.x - 1] : 0;
        int excl = incl[g] - deg[g] + off;
        row_ptr[g] = excl;
        cur[g] = excl;
    }
    if (g == 0) row_ptr[N] = E;
}

// ---- CSR placement: 4B scatter only ----------------------------------------
__global__ __launch_bounds__(256) void place_k(
    const int* __restrict__ edst, int* __restrict__ cur,
    int* __restrict__ perm, int E)
{
    int e = blockIdx.x * blockDim.x + threadIdx.x;
    if (e >= E) return;
    int p = atomicAdd(&cur[edst[e]], 1);
    perm[p] = e;
}

// ---- coalesced payload fill: esrc2 + per-layer cattr4 ----------------------
__global__ __launch_bounds__(256) void fill_k(
    const int* __restrict__ perm, const int* __restrict__ esrc,
    const int* __restrict__ edst, const float* __restrict__ pos,
    const float* __restrict__ rtab,
    int* __restrict__ esrc2, float4* __restrict__ cattr4, int E)
{
    int p = blockIdx.x * blockDim.x + threadIdx.x;
    if (p >= E) return;
    int e = perm[p];
    int s = esrc[e], d = edst[e];
    float vx = pos[3 * s + 0] - pos[3 * d + 0];
    float vy = pos[3 * s + 1] - pos[3 * d + 1];
    float vz = pos[3 * s + 2] - pos[3 * d + 2];
    float len = sqrtf(vx * vx + vy * vy + vz * vz);
    float inv = 1.f / (len + 1e-9f);
    const float S3 = 1.7320508075688772f;
    float ay = S3 * vy * inv, az = S3 * vz * inv, ax = S3 * vx * inv;

    float xx = fminf(len * ((float)TAB / 5.f), (float)TAB);
    int i = min((int)xx, TAB - 1);
    float f = xx - (float)i;

    esrc2[p] = s;
#pragma unroll
    for (int l = 0; l < Lk; l++) {
        float a = rtab[l * (TAB + 1) + i];
        float b = rtab[l * (TAB + 1) + i + 1];
        float c = a + (b - a) * f;
        cattr4[(size_t)l * E + p] = make_float4(c, c * ay, c * az, c * ax);
    }
}

// ---- embed: h fp32 + packed bf16 copy --------------------------------------
__global__ __launch_bounds__(256) void embed_k(
    const float* __restrict__ x, const float* __restrict__ We,
    float* __restrict__ h, unsigned* __restrict__ hb, int N)
{
    __shared__ float sW[FinK * Dk];
    for (int i = threadIdx.x; i < FinK * Dk; i += blockDim.x) sW[i] = We[i];
    __syncthreads();
    int tid = blockIdx.x * blockDim.x + threadIdx.x;
    int n = tid >> 5, k = tid & 31;
    if (n >= N) return;
    float acc = 0.f;
#pragma unroll
    for (int i = 0; i < FinK; i++) acc += x[n * FinK + i] * sW[i * Dk + k];
    h[(size_t)n * Dk + k] = acc;
    float partner = __shfl(acc, k | 1, 32);  // odd-lane value
    if ((k & 1) == 0) hb[(size_t)n * 16 + (k >> 1)] = pack_bf16_rne(acc, partner);
}

// ---- per-layer fused aggregate + tensor-product contraction ----------------
__global__ __launch_bounds__(256) void agg_tp_k(
    const unsigned* __restrict__ hb_in,   // [N,16] packed bf16 (layer input)
    const float4* __restrict__ cattr4,    // [E] c*(1,ay,az,ax), CSR order
    const int* __restrict__ esrc2, const int* __restrict__ row_ptr,
    const float* __restrict__ Wl,         // [32,4,32] = W_tp[l]
    float* __restrict__ h,                // fp32 state, in-place residual
    unsigned* __restrict__ hb_out,        // [N,16] packed bf16 (layer output)
    int N)
{
    int tid = blockIdx.x * blockDim.x + threadIdx.x;
    int n = tid >> 5, k = tid & 31;
    if (n >= N) return;
    int r0 = row_ptr[n], r1 = row_ptr[n + 1];
    int kh = (k >> 1);
    bool hi = (k & 1);

    float a0 = 0.f, a1 = 0.f, a2 = 0.f, a3 = 0.f;

    // Chunk-8 edge loop: all 8 gathers + 8 cattr loads in flight per chunk.
    for (int base = r0; base < r1; base += 8) {
        // phase 1: one coalesced index load (lanes 0-7 carry the 8 indices)
        int tld = base + (k & 7);
        int idx = esrc2[min(tld, r1 - 1)];

#define EXTRACT(J) int s##J = __shfl(idx, J, 32);
        EXTRACT(0) EXTRACT(1) EXTRACT(2) EXTRACT(3)
        EXTRACT(4) EXTRACT(5) EXTRACT(6) EXTRACT(7)
#undef EXTRACT

        // phase 2: issue all independent loads back-to-back
#define GATHER(J) unsigned u##J = hb_in[(size_t)s##J * 16 + kh];
        GATHER(0) GATHER(1) GATHER(2) GATHER(3)
        GATHER(4) GATHER(5) GATHER(6) GATHER(7)
#undef GATHER
#define CLOAD(J) float4 ca##J = cattr4[min(base + J, r1 - 1)];
        CLOAD(0) CLOAD(1) CLOAD(2) CLOAD(3)
        CLOAD(4) CLOAD(5) CLOAD(6) CLOAD(7)
#undef CLOAD

        // phase 3: predicated FMA block
#define ACCUM(J) { \
        float hk = hi ? __uint_as_float(u##J & 0xFFFF0000u) \
                      : __uint_as_float(u##J << 16); \
        hk = (base + J < r1) ? hk : 0.f; \
        a0 += ca##J.x * hk; a1 += ca##J.y * hk; \
        a2 += ca##J.z * hk; a3 += ca##J.w * hk; }
        ACCUM(0) ACCUM(1) ACCUM(2) ACCUM(3)
        ACCUM(4) ACCUM(5) ACCUM(6) ACCUM(7)
#undef ACCUM
    }

    // Contract: out[k] = sum_i sum_a acc_i[a] * W[i,a,k]
    float out = 0.f;
#pragma unroll
    for (int j = 0; j < Dk; j++) {
        float b0 = __shfl(a0, j, 32);
        float b1 = __shfl(a1, j, 32);
        float b2 = __shfl(a2, j, 32);
        float b3 = __shfl(a3, j, 32);
        const float* w = Wl + j * 128 + k;
        out += b0 * w[0] + b1 * w[32] + b2 * w[64] + b3 * w[96];
    }

    float hn = h[(size_t)n * Dk + k] + out;
    h[(size_t)n * Dk + k] = hn;
    float partner = __shfl(hn, k | 1, 32);
    if ((k & 1) == 0) hb_out[(size_t)n * 16 + kh] = pack_bf16_rne(hn, partner);
}

// ---- pool / final ----------------------------------------------------------
constexpr int POOL_NPB = 512;
__global__ __launch_bounds__(256) void pool_k(
    const float* __restrict__ h, const int* __restrict__ batch,
    float* __restrict__ gsum, float* __restrict__ cnt, int N)
{
    int k = threadIdx.x & 31;
    int row = threadIdx.x >> 5;
    int start = blockIdx.x * POOL_NPB;
    int end = min(start + POOL_NPB, N);
    int curg = -1;
    float acc = 0.f, cacc = 0.f;
    for (int n = start + row; n < end; n += 8) {
        int g = batch[n];
        float v = h[(size_t)n * Dk + k];
        if (g != curg) {
            if (curg >= 0) {
                unsafeAtomicAdd(&gsum[curg * Dk + k], acc);
                if (k == 0) unsafeAtomicAdd(&cnt[curg], cacc);
            }
            curg = g; acc = 0.f; cacc = 0.f;
        }
        acc += v; cacc += 1.f;
    }
    if (curg >= 0) {
        unsafeAtomicAdd(&gsum[curg * Dk + k], acc);
        if (k == 0) unsafeAtomicAdd(&cnt[curg], cacc);
    }
}

__global__ __launch_bounds__(64) void final_k(
    const float* __restrict__ gsum, const float* __restrict__ cnt,
    const float* __restrict__ Wdec, const float* __restrict__ orient,
    float* __restrict__ out, int G)
{
    int g = blockIdx.x * blockDim.x + threadIdx.x;
    if (g >= G) return;
    float ic = 1.f / fmaxf(cnt[g], 1.f);
    float c0 = 0.f, c1 = 0.f, c2 = 0.f, c3 = 0.f;
#pragma unroll
    for (int i = 0; i < Dk; i++) {
        float gv = gsum[g * Dk + i] * ic;
        c0 += gv * Wdec[i * 4 + 0];
        c1 += gv * Wdec[i * 4 + 1];
        c2 += gv * Wdec[i * 4 + 2];
        c3 += gv * Wdec[i * 4 + 3];
    }
    float th = orient[g * 2 + 0], ph = orient[g * 2 + 1];
    float st = sinf(th), ct = cosf(th), sp = sinf(ph), cp = cosf(ph);
    float qx = st * cp, qy = st * sp, qz = ct;
    const float S3 = 1.7320508075688772f;
    out[g] = c0 + c1 * S3 * qy + c2 * S3 * qz + c3 * S3 * qx;
}

extern "C" void kernel_launch(void* const* d_in, const int* in_sizes, int n_in,
                              void* d_out, int out_size, void* d_ws, size_t ws_size,
                              hipStream_t stream) {
    const float* pos     = (const float*)d_in[0];
    const float* x       = (const float*)d_in[1];
    const float* orient  = (const float*)d_in[2];
    const float* W_embed = (const float*)d_in[3];
    const float* W_tp    = (const float*)d_in[4];
    const float* W_fc1   = (const float*)d_in[5];
    const float* W_fc2   = (const float*)d_in[6];
    const float* W_dec   = (const float*)d_in[7];
    const int*   esrc    = (const int*)d_in[8];
    const int*   edst    = (const int*)d_in[9];
    const int*   batch   = (const int*)d_in[10];

    const int N = in_sizes[0] / 3;
    const int E = in_sizes[8];
    const int G = in_sizes[2] / 2;
    const int NB = (N + SCB - 1) / SCB;  // scan blocks (<=512 required)

    // ws layout: cattr4 f4[3E] | h f[32N] | hb0 u[16N] | hb1 u[16N] | gsum f[32G] |
    //   cnt f[G] | rtab f[3(TAB+1)] | esrc2 i[E] | perm i[E] | deg i[N] | incl i[N] |
    //   row_ptr i[N+1] | cur i[N] | bsum i[512]
    float*    ws     = (float*)d_ws;
    float4*   cattr4 = (float4*)ws;
    float*    h      = ws + (size_t)12 * E;
    unsigned* hb0    = (unsigned*)(h + (size_t)Dk * N);
    unsigned* hb1    = hb0 + (size_t)16 * N;
    float*    gsum   = (float*)(hb1 + (size_t)16 * N);
    float*    cnt    = gsum + (size_t)Dk * G;
    float*    rtab   = cnt + G;
    int*      esrc2  = (int*)(rtab + 3 * (TAB + 1));
    int*      perm   = esrc2 + E;
    int*      deg    = perm + E;
    int*      incl   = deg + N;
    int*      row_ptr= incl + N;
    int*      cur    = row_ptr + (N + 1);
    int*      bsum   = cur + N;

    hipMemsetAsync(deg, 0, (size_t)N * sizeof(int), stream);
    hipMemsetAsync(gsum, 0, (size_t)(Dk * G + G) * sizeof(float), stream);

    {
        dim3 grid((TAB + 1 + 255) / 256, Lk);
        radial_tab_k<<<grid, 256, 0, stream>>>(W_fc1, W_fc2, rtab);
    }
    hist_k<<<(E + 255) / 256, 256, 0, stream>>>(edst, deg, E);
    scan1_k<<<NB, SCB, 0, stream>>>(deg, incl, bsum, N);
    scan2_k<<<1, 512, 0, stream>>>(bsum, NB);
    scan3_k<<<NB, SCB, 0, stream>>>(deg, incl, bsum, row_ptr, cur, N, E);

    place_k<<<(E + 255) / 256, 256, 0, stream>>>(edst, cur, perm, E);
    fill_k<<<(E + 255) / 256, 256, 0, stream>>>(
        perm, esrc, edst, pos, rtab, esrc2, cattr4, E);
    embed_k<<<(N * 32 + 255) / 256, 256, 0, stream>>>(x, W_embed, h, hb0, N);

    unsigned* hbuf[2] = {hb0, hb1};
    for (int l = 0; l < Lk; l++) {
        agg_tp_k<<<(N * 32 + 255) / 256, 256, 0, stream>>>(
            hbuf[l & 1], cattr4 + (size_t)l * E, esrc2, row_ptr,
            W_tp + (size_t)l * Dk * 4 * Dk, h, hbuf[(l + 1) & 1], N);
    }

    pool_k<<<(N + POOL_NPB - 1) / POOL_NPB, 256, 0, stream>>>(h, batch, gsum, cnt, N);
    final_k<<<(G + 63) / 64, 64, 0, stream>>>(gsum, cnt, W_dec, orient, (float*)d_out, G);
}

// Round 12
// 487.981 us; speedup vs baseline: 1.0361x; 1.0361x over previous
//
#include <hip/hip_runtime.h>

// ---------------------------------------------------------------------------
// SimpleEquivariantNetwork: 3-layer equivariant message passing.
//   Bilinearity: aggregate raw h first, contract with W_tp after:
//     h_new[d,k] = sum_i sum_a W[i,a,k] * Agg[d,a,i]
//   TA-throughput insight (R11): the contraction's 128 scalar W loads/node
//   dominated VMEM instruction issue (~300/wave * 4cyc = the 91us wall).
//   Fix: transposed W copy -> 32 dwordx4/node; bf16-packed acc broadcast
//   -> 2 shfl per j instead of 4.
// ---------------------------------------------------------------------------

constexpr int Dk  = 32;   // feature dim D
constexpr int Hk  = 64;   // radial hidden
constexpr int NBk = 10;   // radial basis
constexpr int Lk  = 3;    // layers
constexpr int FinK = 16;  // input features
constexpr int TAB = 8192; // radial table intervals over [0,5]
constexpr int SCB = 256;  // scan block size

__device__ __forceinline__ float sus(float x) {
    return x > 0.f ? __expf(-1.f / x) : 0.f;
}

__device__ __forceinline__ unsigned pack_bf16_rne(float a, float b) {
    unsigned ua = __float_as_uint(a), ub = __float_as_uint(b);
    ua += 0x7FFFu + ((ua >> 16) & 1u);
    ub += 0x7FFFu + ((ub >> 16) & 1u);
    return (ua >> 16) | (ub & 0xFFFF0000u);
}

// ---- radial table ----------------------------------------------------------
__global__ __launch_bounds__(256) void radial_tab_k(
    const float* __restrict__ Wfc1, const float* __restrict__ Wfc2,
    float* __restrict__ rtab)
{
    int l = blockIdx.y;
    __shared__ float sW1[NBk * Hk];
    __shared__ float sW2[Hk];
    for (int j = threadIdx.x; j < NBk * Hk; j += blockDim.x) sW1[j] = Wfc1[l * NBk * Hk + j];
    for (int j = threadIdx.x; j < Hk; j += blockDim.x) sW2[j] = Wfc2[l * Hk + j];
    __syncthreads();

    int i = blockIdx.x * blockDim.x + threadIdx.x;
    if (i > TAB) return;
    float len = 5.f * (float)i / (float)TAB;
    const float C_EMB = (float)(1.14136 * 7.3890560989306495);
    float t = len * 2.2f;
    float emb[NBk];
#pragma unroll
    for (int j = 0; j < NBk; j++) {
        float d1 = t - (float)j;
        float d2 = (float)(j + 2) - t;
        emb[j] = C_EMB * sus(d1) * sus(d2);
    }
    const float C_OUT = (float)(0.125 * 0.08838834764831845 * 0.2581988897471611);
    float r = 0.f;
    for (int j = 0; j < Hk; j++) {
        float a = 0.f;
#pragma unroll
        for (int b = 0; b < NBk; b++) a += emb[b] * sW1[b * Hk + j];
        float sg = 1.f / (1.f + __expf(-a));
        r += a * sg * sW2[j];
    }
    rtab[l * (TAB + 1) + i] = r * C_OUT;
}

// ---- W_tp transpose: Wt[l][j][k][a] = W_tp[l][j][a][k] ---------------------
__global__ __launch_bounds__(256) void wtr_k(
    const float* __restrict__ Wtp, float* __restrict__ Wt)
{
    int t = blockIdx.x * blockDim.x + threadIdx.x;
    if (t >= Lk * Dk * Dk * 4) return;
    int a = t & 3, k = (t >> 2) & 31, j = (t >> 7) & 31, l = t >> 12;
    Wt[t] = Wtp[l * 4096 + j * 128 + a * 32 + k];
}

// ---- counting sort by dst --------------------------------------------------
__global__ __launch_bounds__(256) void hist_k(
    const int* __restrict__ edst, int* __restrict__ deg, int E)
{
    int e = blockIdx.x * blockDim.x + threadIdx.x;
    if (e < E) atomicAdd(&deg[edst[e]], 1);
}

__global__ __launch_bounds__(SCB) void scan1_k(
    const int* __restrict__ deg, int* __restrict__ incl,
    int* __restrict__ bsum, int N)
{
    __shared__ int s[SCB];
    int g = blockIdx.x * SCB + threadIdx.x;
    s[threadIdx.x] = (g < N) ? deg[g] : 0;
    __syncthreads();
    for (int off = 1; off < SCB; off <<= 1) {
        int t = (threadIdx.x >= off) ? s[threadIdx.x - off] : 0;
        __syncthreads();
        s[threadIdx.x] += t;
        __syncthreads();
    }
    if (g < N) incl[g] = s[threadIdx.x];
    if (threadIdx.x == SCB - 1) bsum[blockIdx.x] = s[threadIdx.x];
}

__global__ __launch_bounds__(512) void scan2_k(int* __restrict__ bsum, int nb)
{
    __shared__ int s[512];
    s[threadIdx.x] = (threadIdx.x < nb) ? bsum[threadIdx.x] : 0;
    __syncthreads();
    for (int off = 1; off < 512; off <<= 1) {
        int t = (threadIdx.x >= off) ? s[threadIdx.x - off] : 0;
        __syncthreads();
        s[threadIdx.x] += t;
        __syncthreads();
    }
    if (threadIdx.x < nb) bsum[threadIdx.x] = s[threadIdx.x];
}

__global__ __launch_bounds__(SCB) void scan3_k(
    const int* __restrict__ deg, const int* __restrict__ incl,
    const int* __restrict__ bsum, int* __restrict__ row_ptr,
    int* __restrict__ cur, int N, int E)
{
    int g = blockIdx.x * SCB + threadIdx.x;
    if (g < N) {
        int off = (blockIdx.x > 0) ? bsum[blockIdx.x - 1] : 0;
        int excl = incl[g] - deg[g] + off;
        row_ptr[g] = excl;
        cur[g] = excl;
    }
    if (g == 0) row_ptr[N] = E;
}

// ---- CSR placement: 4B scatter only ----------------------------------------
__global__ __launch_bounds__(256) void place_k(
    const int* __restrict__ edst, int* __restrict__ cur,
    int* __restrict__ perm, int E)
{
    int e = blockIdx.x * blockDim.x + threadIdx.x;
    if (e >= E) return;
    int p = atomicAdd(&cur[edst[e]], 1);
    perm[p] = e;
}

// ---- coalesced payload fill: esrc2 + per-layer cattr4 ----------------------
__global__ __launch_bounds__(256) void fill_k(
    const int* __restrict__ perm, const int* __restrict__ esrc,
    const int* __restrict__ edst, const float* __restrict__ pos,
    const float* __restrict__ rtab,
    int* __restrict__ esrc2, float4* __restrict__ cattr4, int E)
{
    int p = blockIdx.x * blockDim.x + threadIdx.x;
    if (p >= E) return;
    int e = perm[p];
    int s = esrc[e], d = edst[e];
    float vx = pos[3 * s + 0] - pos[3 * d + 0];
    float vy = pos[3 * s + 1] - pos[3 * d + 1];
    float vz = pos[3 * s + 2] - pos[3 * d + 2];
    float len = sqrtf(vx * vx + vy * vy + vz * vz);
    float inv = 1.f / (len + 1e-9f);
    const float S3 = 1.7320508075688772f;
    float ay = S3 * vy * inv, az = S3 * vz * inv, ax = S3 * vx * inv;

    float xx = fminf(len * ((float)TAB / 5.f), (float)TAB);
    int i = min((int)xx, TAB - 1);
    float f = xx - (float)i;

    esrc2[p] = s;
#pragma unroll
    for (int l = 0; l < Lk; l++) {
        float a = rtab[l * (TAB + 1) + i];
        float b = rtab[l * (TAB + 1) + i + 1];
        float c = a + (b - a) * f;
        cattr4[(size_t)l * E + p] = make_float4(c, c * ay, c * az, c * ax);
    }
}

// ---- embed: h fp32 + packed bf16 copy --------------------------------------
__global__ __launch_bounds__(256) void embed_k(
    const float* __restrict__ x, const float* __restrict__ We,
    float* __restrict__ h, unsigned* __restrict__ hb, int N)
{
    __shared__ float sW[FinK * Dk];
    for (int i = threadIdx.x; i < FinK * Dk; i += blockDim.x) sW[i] = We[i];
    __syncthreads();
    int tid = blockIdx.x * blockDim.x + threadIdx.x;
    int n = tid >> 5, k = tid & 31;
    if (n >= N) return;
    float acc = 0.f;
#pragma unroll
    for (int i = 0; i < FinK; i++) acc += x[n * FinK + i] * sW[i * Dk + k];
    h[(size_t)n * Dk + k] = acc;
    float partner = __shfl(acc, k | 1, 32);  // odd-lane value
    if ((k & 1) == 0) hb[(size_t)n * 16 + (k >> 1)] = pack_bf16_rne(acc, partner);
}

// ---- per-layer fused aggregate + tensor-product contraction ----------------
__global__ __launch_bounds__(256) void agg_tp_k(
    const unsigned* __restrict__ hb_in,   // [N,16] packed bf16 (layer input)
    const float4* __restrict__ cattr4,    // [E] c*(1,ay,az,ax), CSR order
    const int* __restrict__ esrc2, const int* __restrict__ row_ptr,
    const float4* __restrict__ Wt4,       // [32*32] float4: Wt[j][k][0..3]
    float* __restrict__ h,                // fp32 state, in-place residual
    unsigned* __restrict__ hb_out,        // [N,16] packed bf16 (layer output)
    int N)
{
    int tid = blockIdx.x * blockDim.x + threadIdx.x;
    int n = tid >> 5, k = tid & 31;
    if (n >= N) return;
    int r0 = row_ptr[n], r1 = row_ptr[n + 1];
    int kh = (k >> 1);
    bool hi = (k & 1);

    float a0 = 0.f, a1 = 0.f, a2 = 0.f, a3 = 0.f;

    // Chunk-8 edge loop: all 8 gathers + 8 cattr loads in flight per chunk.
    for (int base = r0; base < r1; base += 8) {
        int tld = base + (k & 7);
        int idx = esrc2[min(tld, r1 - 1)];

#define EXTRACT(J) int s##J = __shfl(idx, J, 32);
        EXTRACT(0) EXTRACT(1) EXTRACT(2) EXTRACT(3)
        EXTRACT(4) EXTRACT(5) EXTRACT(6) EXTRACT(7)
#undef EXTRACT

#define GATHER(J) unsigned u##J = hb_in[(size_t)s##J * 16 + kh];
        GATHER(0) GATHER(1) GATHER(2) GATHER(3)
        GATHER(4) GATHER(5) GATHER(6) GATHER(7)
#undef GATHER
#define CLOAD(J) float4 ca##J = cattr4[min(base + J, r1 - 1)];
        CLOAD(0) CLOAD(1) CLOAD(2) CLOAD(3)
        CLOAD(4) CLOAD(5) CLOAD(6) CLOAD(7)
#undef CLOAD

#define ACCUM(J) { \
        float hk = hi ? __uint_as_float(u##J & 0xFFFF0000u) \
                      : __uint_as_float(u##J << 16); \
        hk = (base + J < r1) ? hk : 0.f; \
        a0 += ca##J.x * hk; a1 += ca##J.y * hk; \
        a2 += ca##J.z * hk; a3 += ca##J.w * hk; }
        ACCUM(0) ACCUM(1) ACCUM(2) ACCUM(3)
        ACCUM(4) ACCUM(5) ACCUM(6) ACCUM(7)
#undef ACCUM
    }

    // Contract: out[k] = sum_j sum_a accbf[j][a] * W[j][a][k]
    // acc broadcast as packed bf16 (2 shfl/j); W as one dwordx4/j from Wt.
    unsigned p01 = pack_bf16_rne(a0, a1);
    unsigned p23 = pack_bf16_rne(a2, a3);
    float out = 0.f;
#pragma unroll
    for (int j = 0; j < Dk; j++) {
        unsigned q01 = __shfl(p01, j, 32);
        unsigned q23 = __shfl(p23, j, 32);
        float4 w = Wt4[j * 32 + k];
        float b0 = __uint_as_float(q01 << 16);
        float b1 = __uint_as_float(q01 & 0xFFFF0000u);
        float b2 = __uint_as_float(q23 << 16);
        float b3 = __uint_as_float(q23 & 0xFFFF0000u);
        out += b0 * w.x + b1 * w.y + b2 * w.z + b3 * w.w;
    }

    float hn = h[(size_t)n * Dk + k] + out;
    h[(size_t)n * Dk + k] = hn;
    float partner = __shfl(hn, k | 1, 32);
    if ((k & 1) == 0) hb_out[(size_t)n * 16 + kh] = pack_bf16_rne(hn, partner);
}

// ---- pool / final ----------------------------------------------------------
constexpr int POOL_NPB = 512;
__global__ __launch_bounds__(256) void pool_k(
    const float* __restrict__ h, const int* __restrict__ batch,
    float* __restrict__ gsum, float* __restrict__ cnt, int N)
{
    int k = threadIdx.x & 31;
    int row = threadIdx.x >> 5;
    int start = blockIdx.x * POOL_NPB;
    int end = min(start + POOL_NPB, N);
    int curg = -1;
    float acc = 0.f, cacc = 0.f;
    for (int n = start + row; n < end; n += 8) {
        int g = batch[n];
        float v = h[(size_t)n * Dk + k];
        if (g != curg) {
            if (curg >= 0) {
                unsafeAtomicAdd(&gsum[curg * Dk + k], acc);
                if (k == 0) unsafeAtomicAdd(&cnt[curg], cacc);
            }
            curg = g; acc = 0.f; cacc = 0.f;
        }
        acc += v; cacc += 1.f;
    }
    if (curg >= 0) {
        unsafeAtomicAdd(&gsum[curg * Dk + k], acc);
        if (k == 0) unsafeAtomicAdd(&cnt[curg], cacc);
    }
}

__global__ __launch_bounds__(64) void final_k(
    const float* __restrict__ gsum, const float* __restrict__ cnt,
    const float* __restrict__ Wdec, const float* __restrict__ orient,
    float* __restrict__ out, int G)
{
    int g = blockIdx.x * blockDim.x + threadIdx.x;
    if (g >= G) return;
    float ic = 1.f / fmaxf(cnt[g], 1.f);
    float c0 = 0.f, c1 = 0.f, c2 = 0.f, c3 = 0.f;
#pragma unroll
    for (int i = 0; i < Dk; i++) {
        float gv = gsum[g * Dk + i] * ic;
        c0 += gv * Wdec[i * 4 + 0];
        c1 += gv * Wdec[i * 4 + 1];
        c2 += gv * Wdec[i * 4 + 2];
        c3 += gv * Wdec[i * 4 + 3];
    }
    float th = orient[g * 2 + 0], ph = orient[g * 2 + 1];
    float st = sinf(th), ct = cosf(th), sp = sinf(ph), cp = cosf(ph);
    float qx = st * cp, qy = st * sp, qz = ct;
    const float S3 = 1.7320508075688772f;
    out[g] = c0 + c1 * S3 * qy + c2 * S3 * qz + c3 * S3 * qx;
}

extern "C" void kernel_launch(void* const* d_in, const int* in_sizes, int n_in,
                              void* d_out, int out_size, void* d_ws, size_t ws_size,
                              hipStream_t stream) {
    const float* pos     = (const float*)d_in[0];
    const float* x       = (const float*)d_in[1];
    const float* orient  = (const float*)d_in[2];
    const float* W_embed = (const float*)d_in[3];
    const float* W_tp    = (const float*)d_in[4];
    const float* W_fc1   = (const float*)d_in[5];
    const float* W_fc2   = (const float*)d_in[6];
    const float* W_dec   = (const float*)d_in[7];
    const int*   esrc    = (const int*)d_in[8];
    const int*   edst    = (const int*)d_in[9];
    const int*   batch   = (const int*)d_in[10];

    const int N = in_sizes[0] / 3;
    const int E = in_sizes[8];
    const int G = in_sizes[2] / 2;
    const int NB = (N + SCB - 1) / SCB;  // scan blocks (<=512 required)

    // ws layout: cattr4 f4[3E] | h f[32N] | hb0 u[16N] | hb1 u[16N] | gsum f[32G] |
    //   cnt f[G] | rtab f[3(TAB+1)] | esrc2 i[E] | perm i[E] | deg i[N] | incl i[N] |
    //   row_ptr i[N+1] | cur i[N] | bsum i[512] | Wt f[3*4096]
    float*    ws     = (float*)d_ws;
    float4*   cattr4 = (float4*)ws;
    float*    h      = ws + (size_t)12 * E;
    unsigned* hb0    = (unsigned*)(h + (size_t)Dk * N);
    unsigned* hb1    = hb0 + (size_t)16 * N;
    float*    gsum   = (float*)(hb1 + (size_t)16 * N);
    float*    cnt    = gsum + (size_t)Dk * G;
    float*    rtab   = cnt + G;
    int*      esrc2  = (int*)(rtab + 3 * (TAB + 1));
    int*      perm   = esrc2 + E;
    int*      deg    = perm + E;
    int*      incl   = deg + N;
    int*      row_ptr= incl + N;
    int*      cur    = row_ptr + (N + 1);
    int*      bsum   = cur + N;
    float*    Wt     = (float*)(bsum + 512);

    hipMemsetAsync(deg, 0, (size_t)N * sizeof(int), stream);
    hipMemsetAsync(gsum, 0, (size_t)(Dk * G + G) * sizeof(float), stream);

    {
        dim3 grid((TAB + 1 + 255) / 256, Lk);
        radial_tab_k<<<grid, 256, 0, stream>>>(W_fc1, W_fc2, rtab);
    }
    wtr_k<<<(Lk * Dk * Dk * 4 + 255) / 256, 256, 0, stream>>>(W_tp, Wt);
    hist_k<<<(E + 255) / 256, 256, 0, stream>>>(edst, deg, E);
    scan1_k<<<NB, SCB, 0, stream>>>(deg, incl, bsum, N);
    scan2_k<<<1, 512, 0, stream>>>(bsum, NB);
    scan3_k<<<NB, SCB, 0, stream>>>(deg, incl, bsum, row_ptr, cur, N, E);

    place_k<<<(E + 255) / 256, 256, 0, stream>>>(edst, cur, perm, E);
    fill_k<<<(E + 255) / 256, 256, 0, stream>>>(
        perm, esrc, edst, pos, rtab, esrc2, cattr4, E);
    embed_k<<<(N * 32 + 255) / 256, 256, 0, stream>>>(x, W_embed, h, hb0, N);

    unsigned* hbuf[2] = {hb0, hb1};
    for (int l = 0; l < Lk; l++) {
        agg_tp_k<<<(N * 32 + 255) / 256, 256, 0, stream>>>(
            hbuf[l & 1], cattr4 + (size_t)l * E, esrc2, row_ptr,
            (const float4*)(Wt + (size_t)l * 4096), h, hbuf[(l + 1) & 1], N);
    }

    pool_k<<<(N + POOL_NPB - 1) / POOL_NPB, 256, 0, stream>>>(h, batch, gsum, cnt, N);
    final_k<<<(G + 63) / 64, 64, 0, stream>>>(gsum, cnt, W_dec, orient, (float*)d_out, G);
}